// Round 2
// baseline (643.205 us; speedup 1.0000x reference)
//
#include <hip/hip_runtime.h>
#include <cstdint>

// out = G @ (x @ W^T + b)      [8192,8192] @ [8192,128]
// mask is ignored: mask == (G==0), so where(mask,0,G) == G identically.
#define NN 8192   // nodes
#define KD 256    // in_dim
#define HD 128    // hidden

// R5: two-pass G. R0 (phase rotation) and R4 (4x per-row visit size) both
// moved nothing -> the wall is the COLLECTIVE footprint: all 8192 rows in
// flight as scattered sub-KB pieces. Sequential sweeps provably run at
// 6.3-6.6 TB/s on this chip (fill, m13 copy). So:
//   Pass 1: grid-stride fully-sequential read of G fp32 (fill-like pattern),
//           convert bf16, write 128 MB Gp packed panel-major with the LDS
//           XOR swizzle PRE-APPLIED (linear gld_lds dest + swizzled source).
//   Pass 2: 256 blocks x 32-row panel x full K. Per-block G read = one
//           contiguous 512 KB monotone sweep. ht B-frags direct from L2.
//           Full-K fp32 acc -> direct out store. No split-K, no reduce.
#define MROWS 32              // rows per panel
#define BKF   512             // k floats per pipeline stage
#define NSTEP (NN / BKF)      // 16 stages
#define STG_US  (MROWS * BKF)       // 16384 ushorts = 32 KB per stage
#define PANEL_B ((size_t)NN * MROWS * 2)  // 512 KB per panel

typedef __attribute__((ext_vector_type(4))) float   f32x4;
typedef __attribute__((ext_vector_type(8))) __bf16  bf16x8;
typedef __attribute__((ext_vector_type(8))) unsigned short ushort8;

// fp32 -> bf16 round-to-nearest-even
static __device__ __forceinline__ unsigned short f2bf(float f) {
  unsigned u = __builtin_bit_cast(unsigned, f);
  u += 0x7FFFu + ((u >> 16) & 1u);
  return (unsigned short)(u >> 16);
}

static __device__ __forceinline__ bf16x8 pack8(const float4 a, const float4 b) {
  ushort8 u;
  u[0] = f2bf(a.x); u[1] = f2bf(a.y); u[2] = f2bf(a.z); u[3] = f2bf(a.w);
  u[4] = f2bf(b.x); u[5] = f2bf(b.y); u[6] = f2bf(b.z); u[7] = f2bf(b.w);
  return __builtin_bit_cast(bf16x8, u);
}

#define GLD_LDS16(g, l)                                                        \
  __builtin_amdgcn_global_load_lds(                                            \
      (const __attribute__((address_space(1))) void*)(g),                      \
      (__attribute__((address_space(3))) void*)(l), 16, 0, 0)

// ---------------------------------------------------------------------------
// Kernel A: ht[n][m] = sum_k x[m][k]*W[n][k] + b[n], bf16, [HD][NN].
// ---------------------------------------------------------------------------
__global__ __launch_bounds__(64) void fc_ht_kernel(
    const float* __restrict__ x, const float* __restrict__ W,
    const float* __restrict__ bias, unsigned short* __restrict__ ht)
{
  const int lane = threadIdx.x & 63;
  const int l15  = lane & 15;
  const int lq   = lane >> 4;
  const int m0   = blockIdx.x * 16;

  f32x4 acc[8];
#pragma unroll
  for (int t = 0; t < 8; ++t) acc[t] = (f32x4)0.0f;

  const float* xr = x + (size_t)(m0 + l15) * KD;
#pragma unroll 1
  for (int s = 0; s < KD / 32; ++s) {
    const int k = s * 32 + lq * 8;
    const bf16x8 af = pack8(*(const float4*)(xr + k), *(const float4*)(xr + k + 4));
#pragma unroll
    for (int t = 0; t < 8; ++t) {
      const float* wr = W + (size_t)(t * 16 + l15) * KD + k;
      const bf16x8 bfr = pack8(*(const float4*)wr, *(const float4*)(wr + 4));
      acc[t] = __builtin_amdgcn_mfma_f32_16x16x32_bf16(af, bfr, acc[t], 0, 0, 0);
    }
  }

  // C/D layout: col = lane&15, row = (lane>>4)*4 + reg.
#pragma unroll
  for (int t = 0; t < 8; ++t) {
    const int n  = t * 16 + l15;
    const float bv = bias[n];
    const int mr = m0 + lq * 4;
    uint2 v;
    v.x = (unsigned)f2bf(acc[t][0] + bv) | ((unsigned)f2bf(acc[t][1] + bv) << 16);
    v.y = (unsigned)f2bf(acc[t][2] + bv) | ((unsigned)f2bf(acc[t][3] + bv) << 16);
    *(uint2*)(ht + (size_t)n * NN + mr) = v;
  }
}

// ---------------------------------------------------------------------------
// Kernel P1: convert G fp32 -> packed/swizzled bf16 panels Gp.
// Read pattern = fill-like sequential sweep (the one pattern measured at
// ~6.3-6.6 TB/s). Each thread: one float4 per iter at linear index.
// Gp byte layout: panel t (row/32) * 512KB + stage s (k/512) * 32KB
//                 + rlocal*1024 + ((kl>>3) ^ (rlocal&7))*16 + (kl&7)*2
// (kl = k%512). This is exactly the linear LDS image spmm stages, with the
// read-side XOR bank swizzle pre-applied on the source (guide G21).
// ---------------------------------------------------------------------------
__global__ __launch_bounds__(256) void convert_kernel(
    const float* __restrict__ G, unsigned short* __restrict__ gp)
{
  const int g = blockIdx.x * 256 + threadIdx.x;   // 0..524287
#pragma unroll 1
  for (int it = 0; it < 32; ++it) {
    const size_t idx4 = (size_t)it * 524288 + g;  // float4 index, sequential sweep
    const float4 v = ((const float4*)G)[idx4];
    const size_t ke = idx4 * 4;                   // float index in G
    const int row = (int)(ke >> 13);              // /8192
    const int kk  = (int)(ke & 8191);
    const int rl  = row & 31;
    const int s   = kk >> 9;
    const int kl  = kk & 511;
    const int c   = (kl >> 3) ^ (rl & 7);
    uint2 w;
    w.x = (unsigned)f2bf(v.x) | ((unsigned)f2bf(v.y) << 16);
    w.y = (unsigned)f2bf(v.z) | ((unsigned)f2bf(v.w) << 16);
    *(uint2*)((char*)gp + (size_t)(row >> 5) * PANEL_B + (size_t)s * 32768 +
              rl * 1024 + c * 16 + (kl & 7) * 2) = w;
  }
}

// ---------------------------------------------------------------------------
// Kernel B: spmm. 256 blocks, 512 threads (8 waves = 2m x 4n), full K.
// G: one contiguous 512 KB panel sweep via global_load_lds (linear dest,
// source already packed+swizzled). ht: direct 16B L2 loads per B-frag.
// A ds_read: byte = arow*1024 + (((ksub*4+lq) ^ (arow&7))*16 -> rows r,r+8
// share a bank (2-way = free), 8 chunk slots cover all 32 banks.
// ---------------------------------------------------------------------------
__global__ __launch_bounds__(512, 2) void spmm_kernel(
    const unsigned short* __restrict__ gp,
    const unsigned short* __restrict__ ht,
    float* __restrict__ out)
{
  __shared__ unsigned short gsh[2][STG_US];   // 2 x 32 KB

  const int tid  = threadIdx.x;
  const int lane = tid & 63;
  const int wave = tid >> 6;
  const int l15  = lane & 15;
  const int lq   = lane >> 4;
  const int wm   = wave >> 2;        // 0..1  (16-row half)
  const int wn   = wave & 3;         // 0..3  (32-col quarter)
  const int m0   = blockIdx.x * MROWS;
  const unsigned short* pg = gp + (size_t)blockIdx.x * (PANEL_B / 2);

  f32x4 acc[2];
  acc[0] = (f32x4)0.0f;
  acc[1] = (f32x4)0.0f;

  // stage = 32 KB = 2048 x 16B lane-loads = 4 per thread; source linear.
#define STAGE(s_, buf_)                                                        \
  do {                                                                         \
    _Pragma("unroll")                                                          \
    for (int i = 0; i < 4; ++i) {                                              \
      const int e = i * 512 + tid;                                             \
      GLD_LDS16(pg + (size_t)(s_) * STG_US + e * 8, &gsh[buf_][e * 8]);        \
    }                                                                          \
  } while (0)

  STAGE(0, 0);

  const int arow  = wm * 16 + l15;            // A row this lane loads
  const int abase = arow * 1024;              // byte base in stage
  const int asw   = arow & 7;

#pragma unroll 1
  for (int s = 0; s < NSTEP; ++s) {
    __syncthreads();                          // vmcnt(0) drain: buf[s&1] ready
    if (s + 1 < NSTEP) STAGE(s + 1, (s + 1) & 1);

    const int b = s & 1;
    const unsigned short* hr0 = ht + (size_t)(wn * 32 + l15) * NN + s * BKF + lq * 8;
    const unsigned short* hr1 = hr0 + (size_t)16 * NN;

#pragma unroll
    for (int kc = 0; kc < 4; ++kc) {          // 4 chunks of 4 ksubs (k=128)
      uint4 hb0[4], hb1[4];
      bf16x8 af[4];
#pragma unroll
      for (int j = 0; j < 4; ++j) {
        const int ksub = kc * 4 + j;
        hb0[j] = *(const uint4*)(hr0 + ksub * 32);
        hb1[j] = *(const uint4*)(hr1 + ksub * 32);
        const int c = (ksub * 4 + lq) ^ asw;
        af[j] = *(const bf16x8*)((const char*)&gsh[b][0] + abase + c * 16);
      }
#pragma unroll
      for (int j = 0; j < 4; ++j) {
        acc[0] = __builtin_amdgcn_mfma_f32_16x16x32_bf16(
            af[j], __builtin_bit_cast(bf16x8, hb0[j]), acc[0], 0, 0, 0);
        acc[1] = __builtin_amdgcn_mfma_f32_16x16x32_bf16(
            af[j], __builtin_bit_cast(bf16x8, hb1[j]), acc[1], 0, 0, 0);
      }
    }
  }

  // epilogue: C/D col=lane&15, row=lq*4+reg. Direct final store.
  float* po = out + (size_t)(m0 + wm * 16 + lq * 4) * HD + wn * 32 + l15;
#pragma unroll
  for (int t = 0; t < 2; ++t)
#pragma unroll
    for (int r = 0; r < 4; ++r)
      po[(size_t)r * HD + t * 16] = acc[t][r];
}

extern "C" void kernel_launch(void* const* d_in, const int* in_sizes, int n_in,
                              void* d_out, int out_size, void* d_ws, size_t ws_size,
                              hipStream_t stream) {
  const float* x = (const float*)d_in[0];
  const float* G = (const float*)d_in[1];
  // d_in[2] = mask: NEVER read. mask == (G==0) => where(mask,0,G) == G.
  const float* W = (const float*)d_in[3];
  const float* b = (const float*)d_in[4];
  float* out = (float*)d_out;

  unsigned short* ht = (unsigned short*)d_ws;                        // 2 MB
  unsigned short* gp = (unsigned short*)((char*)d_ws + (4u << 20));  // 128 MB

  convert_kernel<<<2048, 256, 0, stream>>>(G, gp);
  fc_ht_kernel<<<NN / 16, 64, 0, stream>>>(x, W, b, ht);
  spmm_kernel<<<NN / MROWS, 512, 0, stream>>>(gp, ht, out);
}

// Round 4
// 523.946 us; speedup vs baseline: 1.2276x; 1.2276x over previous
//
#include <hip/hip_runtime.h>
#include <cstdint>

// out = G @ (x @ W^T + b)      [8192,8192] @ [8192,128]
// mask is ignored: mask == (G==0), so where(mask,0,G) == G identically.
#define NN 8192   // nodes
#define KD 256    // in_dim
#define HD 128    // hidden

// R6 (resubmit; R6 bench was an infra failure, kernel never ran):
// reg-staged G (T14). R0/R4/R5 showed the G wall is NOT the address
// pattern. All prior spmm used global_load_lds + __syncthreads, which
// emits s_waitcnt vmcnt(0) before s_barrier -> drains the LDS-DMA queue
// every stage -> burst/quiet demand oscillation -> ~1.7 TB/s. Plain loads
// to VGPRs are NOT drained at barriers (compiler waits only at the
// ds_write use, placed after compute). Issue order: hb (L2) first, G
// last, so hb's wait is vmcnt(4) and the G prefetch stays in flight
// across both barriers. bf16 convert happens BEFORE ds_write: LDS stage
// is 8 KB, af reads are direct ds_read_b128 (XOR-swizzled, uniform banks).
#define SPLITK 4
#define KS (NN / SPLITK)   // 2048 k per block
#define BK 128             // k floats per stage
#define NSTEP (KS / BK)    // 16 stages
#define MROWS 32           // G rows per block

typedef __attribute__((ext_vector_type(4))) float   f32x4;
typedef __attribute__((ext_vector_type(8))) __bf16  bf16x8;
typedef __attribute__((ext_vector_type(8))) unsigned short ushort8;

// fp32 -> bf16 round-to-nearest-even
static __device__ __forceinline__ unsigned short f2bf(float f) {
  unsigned u = __builtin_bit_cast(unsigned, f);
  u += 0x7FFFu + ((u >> 16) & 1u);
  return (unsigned short)(u >> 16);
}

static __device__ __forceinline__ bf16x8 pack8(const float4 a, const float4 b) {
  ushort8 u;
  u[0] = f2bf(a.x); u[1] = f2bf(a.y); u[2] = f2bf(a.z); u[3] = f2bf(a.w);
  u[4] = f2bf(b.x); u[5] = f2bf(b.y); u[6] = f2bf(b.z); u[7] = f2bf(b.w);
  return __builtin_bit_cast(bf16x8, u);
}

#define MFMA(a, b, c) __builtin_amdgcn_mfma_f32_16x16x32_bf16((a), (b), (c), 0, 0, 0)

// ---------------------------------------------------------------------------
// Kernel A: ht[n][m] = sum_k x[m][k]*W[n][k] + b[n], bf16, [HD][NN].
// ---------------------------------------------------------------------------
__global__ __launch_bounds__(64) void fc_ht_kernel(
    const float* __restrict__ x, const float* __restrict__ W,
    const float* __restrict__ bias, unsigned short* __restrict__ ht)
{
  const int lane = threadIdx.x & 63;
  const int l15  = lane & 15;
  const int lq   = lane >> 4;
  const int m0   = blockIdx.x * 16;

  f32x4 acc[8];
#pragma unroll
  for (int t = 0; t < 8; ++t) acc[t] = (f32x4)0.0f;

  const float* xr = x + (size_t)(m0 + l15) * KD;
#pragma unroll 1
  for (int s = 0; s < KD / 32; ++s) {
    const int k = s * 32 + lq * 8;
    const bf16x8 af = pack8(*(const float4*)(xr + k), *(const float4*)(xr + k + 4));
#pragma unroll
    for (int t = 0; t < 8; ++t) {
      const float* wr = W + (size_t)(t * 16 + l15) * KD + k;
      const bf16x8 bfr = pack8(*(const float4*)wr, *(const float4*)(wr + 4));
      acc[t] = MFMA(af, bfr, acc[t]);
    }
  }

  // C/D layout: col = lane&15, row = (lane>>4)*4 + reg.
#pragma unroll
  for (int t = 0; t < 8; ++t) {
    const int n  = t * 16 + l15;
    const float bv = bias[n];
    const int mr = m0 + lq * 4;
    uint2 v;
    v.x = (unsigned)f2bf(acc[t][0] + bv) | ((unsigned)f2bf(acc[t][1] + bv) << 16);
    v.y = (unsigned)f2bf(acc[t][2] + bv) | ((unsigned)f2bf(acc[t][3] + bv) << 16);
    *(uint2*)(ht + (size_t)n * NN + mr) = v;
  }
}

// ---------------------------------------------------------------------------
// Kernel B: spmm, reg-staged G. 1024 blocks x 256 thr (4 waves, 4 blocks/CU).
// Per stage: 32 rows x 512 B G read as 4x float4/thread (64 B contiguous),
// converted to bf16, ds_write_b128 x2 into 8 KB buffer. Waves split 128
// n-cols 4x32; each wave reads both 16-row A halves. LDS chunk swizzle
// c ^= (row&7): write banks uniform, read = 4-lane broadcast + 2-way (free).
// ---------------------------------------------------------------------------
__global__ __launch_bounds__(256, 4) void spmm_kernel(
    const float* __restrict__ G, const unsigned short* __restrict__ ht,
    float* __restrict__ P)
{
  __shared__ __align__(16) unsigned short gsh[2][MROWS * BK];   // 2 x 8 KB

  const int tid   = threadIdx.x;
  const int lane  = tid & 63;
  const int wave  = tid >> 6;          // n-quarter 0..3
  const int l15   = lane & 15;
  const int lq    = lane >> 4;
  const int mtile = blockIdx.x >> 2;
  const int ks    = blockIdx.x & 3;
  const int m0    = mtile * MROWS;
  const int kb0   = ks * KS;

  // staging map: row sr = tid>>3, 16-float span starting at (tid&7)*16
  const int sr = tid >> 3;
  const int sc = tid & 7;   // chunk-pair index (chunks 2sc, 2sc+1)
  const float4* gsrc = (const float4*)(G + (size_t)(m0 + sr) * NN + kb0) + sc * 4;
  const int wofs0 = sr * BK + (((sc * 2 + 0) ^ (sr & 7)) * 8);  // ushort offsets
  const int wofs1 = sr * BK + (((sc * 2 + 1) ^ (sr & 7)) * 8);

  const int asw = l15 & 7;
  const unsigned short* hrow = ht + (size_t)(wave * 32 + l15) * NN + kb0 + lq * 8;

  f32x4 acc[2][2];
  acc[0][0] = (f32x4)0.0f; acc[0][1] = (f32x4)0.0f;
  acc[1][0] = (f32x4)0.0f; acc[1][1] = (f32x4)0.0f;

  // prologue: stage 0 (one full-latency stall, once)
  {
    const float4 a = gsrc[0], b2 = gsrc[1], c = gsrc[2], d = gsrc[3];
    *(bf16x8*)&gsh[0][wofs0] = pack8(a, b2);
    *(bf16x8*)&gsh[0][wofs1] = pack8(c, d);
  }
  __syncthreads();

#pragma unroll 1
  for (int s = 0; s < NSTEP; ++s) {
    const int b = s & 1;

    // (1) hb for stage s from L2 — issued FIRST so MFMA's wait is vmcnt(4),
    //     leaving the G prefetch (issued after) in flight.
    uint4 hb[4][2];
#pragma unroll
    for (int ksub = 0; ksub < 4; ++ksub)
#pragma unroll
      for (int t = 0; t < 2; ++t)
        hb[ksub][t] =
            *(const uint4*)(hrow + (size_t)t * 16 * NN + s * BK + ksub * 32);

    // (2) G prefetch for stage s+1 -> registers (NOT drained by barriers)
    float4 n0, n1, n2, n3;
    if (s + 1 < NSTEP) {
      const float4* p = gsrc + (s + 1) * (BK / 4);
      n0 = p[0]; n1 = p[1]; n2 = p[2]; n3 = p[3];
    }

    // (3) compute stage s from gsh[b]
#pragma unroll
    for (int ksub = 0; ksub < 4; ++ksub) {
      const int co = (((ksub * 4 + lq) ^ asw)) * 8;
      const bf16x8 af0 = *(const bf16x8*)&gsh[b][l15 * BK + co];
      const bf16x8 af1 = *(const bf16x8*)&gsh[b][(16 + l15) * BK + co];
      acc[0][0] = MFMA(af0, __builtin_bit_cast(bf16x8, hb[ksub][0]), acc[0][0]);
      acc[0][1] = MFMA(af0, __builtin_bit_cast(bf16x8, hb[ksub][1]), acc[0][1]);
      acc[1][0] = MFMA(af1, __builtin_bit_cast(bf16x8, hb[ksub][0]), acc[1][0]);
      acc[1][1] = MFMA(af1, __builtin_bit_cast(bf16x8, hb[ksub][1]), acc[1][1]);
    }

    __syncthreads();   // (A) all waves done reading gsh[b]
    if (s + 1 < NSTEP) {
      // compiler inserts vmcnt wait for n0..n3 here — after compute, so
      // the HBM latency was hidden under (3).
      *(bf16x8*)&gsh[b ^ 1][wofs0] = pack8(n0, n1);
      *(bf16x8*)&gsh[b ^ 1][wofs1] = pack8(n2, n3);
    }
    __syncthreads();   // (B) gsh[b^1] ready for stage s+1
  }

  // epilogue: split-K partials, P[ks][m][n]. C/D: col=lane&15, row=lq*4+reg.
  float* __restrict__ pp = P + (size_t)ks * NN * HD;
#pragma unroll
  for (int a = 0; a < 2; ++a)
#pragma unroll
    for (int t = 0; t < 2; ++t) {
      const int n  = wave * 32 + t * 16 + l15;
      const int mr = m0 + a * 16 + lq * 4;
#pragma unroll
      for (int r = 0; r < 4; ++r)
        pp[(size_t)(mr + r) * HD + n] = acc[a][t][r];
    }
}

// ---------------------------------------------------------------------------
// Kernel C: out[m][n] = sum_ks P[ks][m][n].
// ---------------------------------------------------------------------------
__global__ __launch_bounds__(256) void reduce_kernel(
    const f32x4* __restrict__ P, f32x4* __restrict__ out)
{
  const int idx = blockIdx.x * 256 + threadIdx.x;   // 0..262143 float4s
  const int S = NN * HD / 4;
  f32x4 s = P[idx];
#pragma unroll
  for (int k = 1; k < SPLITK; ++k) s += P[(size_t)k * S + idx];
  out[idx] = s;
}

extern "C" void kernel_launch(void* const* d_in, const int* in_sizes, int n_in,
                              void* d_out, int out_size, void* d_ws, size_t ws_size,
                              hipStream_t stream) {
  const float* x = (const float*)d_in[0];
  const float* G = (const float*)d_in[1];
  // d_in[2] = mask: NEVER read. mask == (G==0) => where(mask,0,G) == G.
  const float* W = (const float*)d_in[3];
  const float* b = (const float*)d_in[4];
  float* out = (float*)d_out;

  unsigned short* ht = (unsigned short*)d_ws;                  // 2 MB
  float* P = (float*)((char*)d_ws + (4u << 20));               // 16 MB partials

  fc_ht_kernel<<<NN / 16, 64, 0, stream>>>(x, W, b, ht);
  spmm_kernel<<<(NN / MROWS) * SPLITK, 256, 0, stream>>>(G, ht, P);
  reduce_kernel<<<NN * HD / 4 / 256, 256, 0, stream>>>((const f32x4*)P, (f32x4*)out);
}